// Round 10
// baseline (728.551 us; speedup 1.0000x reference)
//
#include <hip/hip_runtime.h>
#include <hip/hip_bf16.h>
#include <hip/hip_fp16.h>

#define N 1024
#define D 128
#define SB 16          // steps per superstep (gi chunk staged in LDS, f16)
#define NSB (N / SB)

typedef __hip_bfloat16 bf16;
typedef __attribute__((ext_vector_type(8))) short bfx8;    // 8 bf16 MFMA A/B frag
typedef __attribute__((ext_vector_type(4))) float fx4;     // MFMA C/D frag
typedef __attribute__((ext_vector_type(8))) unsigned short u16x8;

__device__ __forceinline__ float b2f(bf16 x) { return __bfloat162float(x); }
__device__ __forceinline__ short f2bf_bits(float x) {
    bf16 b = __float2bfloat16(x);
    return *reinterpret_cast<short*>(&b);
}
__device__ __forceinline__ float bfbits2f(unsigned short u) {
    return __uint_as_float(((unsigned int)u) << 16);
}
__device__ __forceinline__ float fastrcp(float x) { return __builtin_amdgcn_rcpf(x); }

__device__ __forceinline__ float fast_tanh(float x) {
    float e = __expf(2.f * x);
    return 1.f - 2.f * fastrcp(e + 1.f);
}
__device__ __forceinline__ float fast_sigmoid(float x) {
    return fastrcp(1.f + __expf(-x));
}

__device__ __forceinline__ float sel4(fx4 v, int r) {
    float x = (r & 1) ? v[1] : v[0];
    float y = (r & 1) ? v[3] : v[2];
    return (r & 2) ? y : x;
}

// flag-dispatched element load (bf16 or fp32 raw input)
__device__ __forceinline__ float ldf(const void* p, int i, int isbf) {
    return isbf ? b2f(((const bf16*)p)[i]) : ((const float*)p)[i];
}

// async 16B global->LDS: HW scatters lane i at ldsbase + i*16
__device__ __forceinline__ void async_copy16(const void* g, void* l) {
    __builtin_amdgcn_global_load_lds((const __attribute__((address_space(1))) void*)g,
                                     (__attribute__((address_space(3))) void*)l, 16, 0, 0);
}

// ---------------- K0: dtype sniff + rflag zero (one dispatch) ----------------
__global__ void sniff_zero_kernel(const unsigned short* __restrict__ xu,
                                  int* __restrict__ flag, int* __restrict__ rflag) {
    int t = threadIdx.x;
    if (blockIdx.x == 0) {
        if (t < 64) {
            int cnt = 0;
#pragma unroll
            for (int k = 0; k < 8; ++k) {
                unsigned short u = xu[2 * (t * 8 + k)];
                int e = (u >> 7) & 0xFF;
                cnt += (e >= 96 && e <= 144) ? 1 : 0;
            }
            for (int off = 32; off > 0; off >>= 1) cnt += __shfl_down(cnt, off);
            if (t == 0) *flag = (cnt > 400) ? 1 : 0;
        }
    } else {
        rflag[(blockIdx.x - 1) * 256 + t] = 0;
    }
}

// ---------------- K1: fused prep — qk + wihT transpose + converts ----------------
// blocks [0,1024): qk row i (reads raw X/Wq/Wk, converts inline)
// blocks [1024,1408): wihT transpose from raw w_ih
// blocks [1408,1440): Xf convert
// block  1440: vf + bihf + bhhf convert
// blocks [1441,1465): whhf convert
__global__ void __launch_bounds__(256) prep_kernel(const void* __restrict__ Xr,
                                                   const void* __restrict__ Wqr,
                                                   const void* __restrict__ Wkr,
                                                   const void* __restrict__ vr,
                                                   const void* __restrict__ wihr,
                                                   const void* __restrict__ whhr,
                                                   const void* __restrict__ bihr,
                                                   const void* __restrict__ bhhr,
                                                   const int* __restrict__ flag,
                                                   float* __restrict__ q, float* __restrict__ kT,
                                                   float* __restrict__ wihT,
                                                   float* __restrict__ Xf, float* __restrict__ vf,
                                                   float* __restrict__ whhf,
                                                   float* __restrict__ bihf,
                                                   float* __restrict__ bhhf) {
    int b = blockIdx.x;
    int t = threadIdx.x;
    int isbf = *flag;
    if (b < 1024) {
        __shared__ float xrow[D];
        if (t < D) xrow[t] = ldf(Xr, b * D + t, isbf);
        __syncthreads();
        if (t < D) {
            float acc = 0.f;
#pragma unroll 8
            for (int c = 0; c < D; ++c) acc += xrow[c] * ldf(Wqr, t * D + c, isbf);
            q[b * D + t] = acc;
        } else {
            int d = t - D;
            float acc = 0.f;
#pragma unroll 8
            for (int c = 0; c < D; ++c) acc += xrow[c] * ldf(Wkr, d * D + c, isbf);
            kT[d * N + b] = acc;
        }
    } else if (b < 1408) {
        int id = (b - 1024) * 256 + t;      // 98304 total
        int c = id / 384;
        int o = id - c * 384;
        wihT[id] = ldf(wihr, o * 256 + c, isbf);
    } else if (b < 1440) {
        int base = (b - 1408) * 4096;
#pragma unroll
        for (int k = 0; k < 16; ++k) {
            int i = base + k * 256 + t;
            Xf[i] = ldf(Xr, i, isbf);
        }
    } else if (b == 1440) {
        if (t < D) vf[t] = ldf(vr, t, isbf);
        for (int o = t; o < 3 * D; o += 256) {
            bihf[o] = ldf(bihr, o, isbf);
            bhhf[o] = ldf(bhhr, o, isbf);
        }
    } else {
        int base = (b - 1441) * 2048;
#pragma unroll
        for (int k = 0; k < 8; ++k) {
            int i = base + k * 256 + t;
            whhf[i] = ldf(whhr, i, isbf);
        }
    }
}

// ================= mega kernel =================
// block 0 = GRU consumer (R6 MFMA engine, SB=16, f16 gi staging, 28.9 KB LDS);
// blocks 1..N = attention producers (7 KB usage) -> 3 blocks/CU (VGPR-capped),
// fixing R9's 1-block/CU producer starvation.
#define SMEM_BYTES 28928   // gi_lds 2*12288 + hist 17*128*2 = 28928

__device__ __forceinline__ void wait_chunk(const int* rflag, int base, int t) {
    if (t < SB) {
        while (__hip_atomic_load(rflag + base + t, __ATOMIC_ACQUIRE,
                                 __HIP_MEMORY_SCOPE_AGENT) == 0) {
            __builtin_amdgcn_s_sleep(1);
        }
    }
    __syncthreads();
}

// ---- attention producer for row i -> gih (f16), release rflag[i] ----
__device__ void attn_body(char* smem, int i,
                          const float* __restrict__ q, const float* __restrict__ kT,
                          const float* __restrict__ v, const float* __restrict__ X,
                          const float* __restrict__ wihT, const float* __restrict__ b_ih,
                          __half* __restrict__ gih, int* __restrict__ rflag) {
    float* qs = (float*)smem;      // D
    float* vs = qs + D;            // D
    float* xr = vs + D;            // D
    float* al = xr + D;            // D
    float* wrow = al + D;          // N
    float* red = wrow + N;         // 256
    int t = threadIdx.x;
    if (t < D) { qs[t] = q[i * D + t]; vs[t] = v[t]; xr[t] = X[i * D + t]; }
    __syncthreads();

    float sj[4];
    int cnt = 0;
    float m = -1e30f;
    for (int j = i + t; j < N; j += 256) {
        float s = 0.f;
#pragma unroll 8
        for (int d = 0; d < D; ++d) s += vs[d] * fast_tanh(qs[d] + kT[d * N + j]);
        sj[cnt++] = s;
        m = fmaxf(m, s);
    }
    red[t] = m;
    __syncthreads();
    for (int st = 128; st > 0; st >>= 1) {
        if (t < st) red[t] = fmaxf(red[t], red[t + st]);
        __syncthreads();
    }
    m = red[0];
    __syncthreads();
    float lsum = 0.f;
    {
        int it = 0;
        for (int j = i + t; j < N; j += 256, ++it) {
            float p = __expf(sj[it] - m);
            wrow[j] = p;
            lsum += p;
        }
    }
    red[t] = lsum;
    __syncthreads();
    for (int st = 128; st > 0; st >>= 1) {
        if (t < st) red[t] += red[t + st];
        __syncthreads();
    }
    float inv = fastrcp(red[0]);
    __syncthreads();

    int d = t & 127, half = t >> 7;
    float acc = 0.f;
    for (int j = i + half; j < N; j += 2) acc += wrow[j] * X[j * D + d];
    if (half) red[d] = acc;
    __syncthreads();
    if (!half) al[d] = (acc + red[d]) * inv;
    __syncthreads();

    for (int o = t; o < 3 * D; o += 256) {
        float a2 = b_ih[o];
        const float* wt = wihT + o;
#pragma unroll 8
        for (int c = 0; c < D; ++c) a2 += xr[c] * wt[c * 384];
#pragma unroll 8
        for (int c = 0; c < D; ++c) a2 += al[c] * wt[(D + c) * 384];
        gih[i * 384 + o] = __float2half(a2);
    }
    __threadfence();
    __syncthreads();
    if (t == 0) __hip_atomic_store(rflag + i, 1, __ATOMIC_RELEASE, __HIP_MEMORY_SCOPE_AGENT);
}

// ---- GRU consumer: R6 MFMA engine, SB=16, f16 gi ----
__device__ void gru_body(char* smem, const __half* __restrict__ gih,
                         const float* __restrict__ w_hh, const float* __restrict__ b_hh,
                         void* __restrict__ out, const int* __restrict__ dflag,
                         const int* __restrict__ rflag) {
    char* gi_lds = smem;                                   // 2 x 12288 B (f16)
    short (*hist)[D] = (short (*)[D])(smem + 24576);       // [SB+1][D]
    int t = threadIdx.x;
    int w = t >> 6;
    int l = t & 63;
    int q = l >> 4;
    int nn = l & 15;
    int isbf = *dflag;

    // A-frags: a[tau][mqi][kc]; A[m=nn][k=32kc+8q+j]
    bfx8 a[3][2][4];
#pragma unroll
    for (int tau = 0; tau < 3; ++tau)
#pragma unroll
        for (int mqi = 0; mqi < 2; ++mqi)
#pragma unroll
            for (int kc = 0; kc < 4; ++kc) {
                int row = 128 * tau + 16 * (2 * w + mqi) + nn;
                int k0 = 32 * kc + 8 * q;
#pragma unroll
                for (int j = 0; j < 8; ++j)
                    a[tau][mqi][kc][j] = f2bf_bits(w_hh[row * D + k0 + j]);
            }
    fx4 bias[3][2];
#pragma unroll
    for (int tau = 0; tau < 3; ++tau)
#pragma unroll
        for (int mqi = 0; mqi < 2; ++mqi)
#pragma unroll
            for (int r = 0; r < 4; ++r)
                bias[tau][mqi][r] = b_hh[128 * tau + 16 * (2 * w + mqi) + 4 * q + r];

    int rsel = l & 3;
    int mqsel = (l >> 3) & 1;
    int drow = 32 * w + 16 * mqsel + 4 * q + rsel;
    float h = 0.f;

    int fr = 1 + (t >> 4);          // flush: hist row fr, 8 cols at fc
    int fc = (t & 15) * 8;

    // wait for rows 0..15, prefetch chunk 0 into buffer 0
    wait_chunk(rflag, 0, t);
    {
        const char* src = (const char*)gih;
#pragma unroll
        for (int c = 0; c < 3; ++c) {
            int seg = w * 3 + c;            // 12 segments x 1024 B
            async_copy16(src + seg * 1024 + l * 16, gi_lds + seg * 1024);
        }
    }

    for (int sb = 0; sb < NSB; ++sb) {
        int cb = sb & 1;
        if (sb == 0) {
            if (t < 64) ((int*)&hist[0][0])[t] = 0;
        } else {
            u16x8 h0 = *(const u16x8*)&hist[fr][fc];
            int orow = (sb - 1) * SB + fr - 1;
            if (isbf) {
                *(u16x8*)((unsigned short*)out + orow * D + fc) = h0;
            } else {
                float* op = (float*)out + orow * D + fc;
                fx4 f0, f1;
#pragma unroll
                for (int j = 0; j < 4; ++j) { f0[j] = bfbits2f(h0[j]); f1[j] = bfbits2f(h0[4 + j]); }
                *(fx4*)op = f0; *(fx4*)(op + 4) = f1;
            }
            if (t < 64) ((int*)&hist[0][0])[t] = ((const int*)&hist[SB][0])[t];
        }
        // drain: chunk sb's prefetch (issued one superstep ago) + flush stores
        asm volatile("s_waitcnt vmcnt(0) lgkmcnt(0)\ns_barrier" ::: "memory");

        if (sb + 1 < NSB) {
            wait_chunk(rflag, (sb + 1) * SB, t);
            const char* src = (const char*)gih + (size_t)(sb + 1) * SB * 384 * 2;
#pragma unroll
            for (int c = 0; c < 3; ++c) {
                int seg = w * 3 + c;
                async_copy16(src + seg * 1024 + l * 16, gi_lds + (cb ^ 1) * 12288 + seg * 1024);
            }
        }

        const char* hrd = (const char*)&hist[0][0] + 16 * q;          // step +256
        const __half* gp = (const __half*)(gi_lds + cb * 12288) + drow; // step +384
        short* hwr = &hist[1][0] + drow;                              // step +128

        for (int s = 0; s < SB; ++s) {
            bfx8 b0 = *(const bfx8*)(hrd);
            bfx8 b1 = *(const bfx8*)(hrd + 64);
            bfx8 b2 = *(const bfx8*)(hrd + 128);
            bfx8 b3 = *(const bfx8*)(hrd + 192);
            float gr = __half2float(gp[0]);
            float gz = __half2float(gp[D]);
            float gn = __half2float(gp[2 * D]);

            fx4 acc[3][2];
#pragma unroll
            for (int tau = 0; tau < 3; ++tau)
#pragma unroll
                for (int mqi = 0; mqi < 2; ++mqi) {
                    fx4 c = bias[tau][mqi];
                    c = __builtin_amdgcn_mfma_f32_16x16x32_bf16(a[tau][mqi][0], b0, c, 0, 0, 0);
                    c = __builtin_amdgcn_mfma_f32_16x16x32_bf16(a[tau][mqi][1], b1, c, 0, 0, 0);
                    c = __builtin_amdgcn_mfma_f32_16x16x32_bf16(a[tau][mqi][2], b2, c, 0, 0, 0);
                    c = __builtin_amdgcn_mfma_f32_16x16x32_bf16(a[tau][mqi][3], b3, c, 0, 0, 0);
                    acc[tau][mqi] = c;
                }

            float ar = sel4(mqsel ? acc[0][1] : acc[0][0], rsel);
            float az = sel4(mqsel ? acc[1][1] : acc[1][0], rsel);
            float an = sel4(mqsel ? acc[2][1] : acc[2][0], rsel);
            float rr = fast_sigmoid(gr + ar);
            float zz = fast_sigmoid(gz + az);
            float nst = fast_tanh(gn + rr * an);
            h = (1.f - zz) * nst + zz * h;
            *hwr = f2bf_bits(h);     // replica lanes, same addr+data: free

            hrd += 256;
            gp += 384;
            hwr += D;
            asm volatile("s_waitcnt lgkmcnt(0)\ns_barrier" ::: "memory");
        }
    }
    // final flush
    {
        u16x8 h0 = *(const u16x8*)&hist[fr][fc];
        int orow = (NSB - 1) * SB + fr - 1;
        if (isbf) {
            *(u16x8*)((unsigned short*)out + orow * D + fc) = h0;
        } else {
            float* op = (float*)out + orow * D + fc;
            fx4 f0, f1;
#pragma unroll
            for (int j = 0; j < 4; ++j) { f0[j] = bfbits2f(h0[j]); f1[j] = bfbits2f(h0[4 + j]); }
            *(fx4*)op = f0; *(fx4*)(op + 4) = f1;
        }
    }
}

__global__ void __launch_bounds__(256, 1) mega_kernel(const float* __restrict__ q,
                                                      const float* __restrict__ kT,
                                                      const float* __restrict__ v,
                                                      const float* __restrict__ X,
                                                      const float* __restrict__ wihT,
                                                      const float* __restrict__ b_ih,
                                                      __half* __restrict__ gih,
                                                      const float* __restrict__ w_hh,
                                                      const float* __restrict__ b_hh,
                                                      void* __restrict__ out,
                                                      const int* __restrict__ dflag,
                                                      int* __restrict__ rflag) {
    __shared__ __align__(16) char smem[SMEM_BYTES];
    if (blockIdx.x != 0) {
        attn_body(smem, (int)blockIdx.x - 1, q, kT, v, X, wihT, b_ih, gih, rflag);
    } else {
        gru_body(smem, gih, w_hh, b_hh, out, dflag, rflag);
    }
}

extern "C" void kernel_launch(void* const* d_in, const int* in_sizes, int n_in,
                              void* d_out, int out_size, void* d_ws, size_t ws_size,
                              hipStream_t stream) {
    (void)in_sizes; (void)n_in; (void)out_size; (void)ws_size;

    float* w0 = (float*)d_ws;
    int*   dflag = (int*)w0;                  // 16 ints
    int*   rflag = (int*)(w0 + 16);           // N row-ready flags
    float* Xf   = w0 + 16 + N;
    float* vf   = Xf   + N * D;
    float* whhf = vf   + D;
    float* bhhf = whhf + 3 * D * D;
    float* bihf = bhhf + 3 * D;
    float* q    = bihf + 3 * D;
    float* kT   = q    + N * D;
    float* wihT = kT   + N * D;
    __half* gih = (__half*)(wihT + 3 * D * 2 * D);   // N x 3D f16

    sniff_zero_kernel<<<5, 256, 0, stream>>>((const unsigned short*)d_in[0], dflag, rflag);

    prep_kernel<<<1465, 256, 0, stream>>>(d_in[0], d_in[1], d_in[2], d_in[3],
                                          d_in[4], d_in[5], d_in[6], d_in[7],
                                          dflag, q, kT, wihT, Xf, vf, whhf, bihf, bhhf);

    mega_kernel<<<1 + N, 256, 0, stream>>>(q, kT, vf, Xf, wihT, bihf, gih,
                                           whhf, bhhf, d_out, dflag, rflag);
}